// Round 4
// baseline (50863.837 us; speedup 1.0000x reference)
//
#include <hip/hip_runtime.h>
#include <math.h>

#define H    256
#define BB   64
#define LL   128
#define LBL  128
#define NSTEP (BB*LL)      // 8192 sequential cell steps
#define GDIM (4*H)         // 1024 gate rows
#define KDIM (4*H)         // 1024 feats dim
#define W5   (5*H)         // 1280 (W_ih leading dim)
#define NWG  16            // recurrence team size
#define NROW (NSTEP + 64)  // tagged-h rows: row r holds h_{r-64}, tag r

typedef unsigned long long ull;

// ---------------------------------------------------------------------------
// K0: init tagged rows 0..63 of HT: (h=0.0f, tag=row). Re-run every launch
//     (workspace is re-poisoned before every timed call).
// ---------------------------------------------------------------------------
__global__ void k_init(ull* __restrict__ HT)
{
    const int r = blockIdx.x;          // 0..63
    const int e = threadIdx.x;         // 0..255
    HT[(ull)r * H + e] = ((ull)(unsigned)r << 32);   // low 32 = 0.0f bits
}

// ---------------------------------------------------------------------------
// K1: PRE[k][row] = bias[row] + sum_j W_ih[row][j] * feats[k][j], j<1024
//     (unchanged from R2 — fp16 output, gate-major rows; proven correct)
// ---------------------------------------------------------------------------
__global__ __launch_bounds__(256) void k_pre(const float* __restrict__ x,
                                             const float* __restrict__ hi,
                                             const float* __restrict__ Wih,
                                             const float* __restrict__ bih,
                                             const float* __restrict__ bhh,
                                             _Float16* __restrict__ PREh)
{
    const int nb = blockIdx.x;   // row-block: rows nb*64 .. +63
    const int t  = blockIdx.y;   // time index == M-block (m_local = b)
    const int tid = threadIdx.x;
    const int tm = tid >> 4, tn = tid & 15;

    __shared__ float As[16][68];
    __shared__ float Bs[16][68];

    const int lm  = tid >> 2;          // 0..63
    const int lk4 = (tid & 3) * 4;     // 0,4,8,12

    float acc[4][4];
#pragma unroll
    for (int i = 0; i < 4; i++)
#pragma unroll
        for (int j = 0; j < 4; j++) acc[i][j] = 0.f;

    for (int j0 = 0; j0 < KDIM; j0 += 16) {
        const int j = j0 + lk4;
        float4 av;
        if (j < 512) av = *(const float4*)(x  + ((size_t)lm * LL + t) * 512 + j);
        else         av = *(const float4*)(hi + ((size_t)lm * LL + t) * 512 + (j - 512));
        float4 bv = *(const float4*)(Wih + (size_t)(nb * 64 + lm) * W5 + j);

        __syncthreads();
        As[lk4 + 0][lm] = av.x; As[lk4 + 1][lm] = av.y;
        As[lk4 + 2][lm] = av.z; As[lk4 + 3][lm] = av.w;
        Bs[lk4 + 0][lm] = bv.x; Bs[lk4 + 1][lm] = bv.y;
        Bs[lk4 + 2][lm] = bv.z; Bs[lk4 + 3][lm] = bv.w;
        __syncthreads();

#pragma unroll
        for (int kk = 0; kk < 16; kk++) {
            float4 a = *(const float4*)&As[kk][tm << 2];
            float4 b = *(const float4*)&Bs[kk][tn << 2];
            acc[0][0] += a.x * b.x; acc[0][1] += a.x * b.y; acc[0][2] += a.x * b.z; acc[0][3] += a.x * b.w;
            acc[1][0] += a.y * b.x; acc[1][1] += a.y * b.y; acc[1][2] += a.y * b.z; acc[1][3] += a.y * b.w;
            acc[2][0] += a.z * b.x; acc[2][1] += a.z * b.y; acc[2][2] += a.z * b.z; acc[2][3] += a.z * b.w;
            acc[3][0] += a.w * b.x; acc[3][1] += a.w * b.y; acc[3][2] += a.w * b.z; acc[3][3] += a.w * b.w;
        }
    }

    const int n0 = nb * 64 + tn * 4;
    float4 b1 = *(const float4*)(bih + n0);
    float4 b2 = *(const float4*)(bhh + n0);
    const float bx = b1.x + b2.x, by = b1.y + b2.y, bz = b1.z + b2.z, bw = b1.w + b2.w;
#pragma unroll
    for (int i = 0; i < 4; i++) {
        const size_t m = (size_t)t * 64 + tm * 4 + i;    // k index
        union { _Float16 h[4]; ull u; } p;
        p.h[0] = (_Float16)(acc[i][0] + bx);
        p.h[1] = (_Float16)(acc[i][1] + by);
        p.h[2] = (_Float16)(acc[i][2] + bz);
        p.h[3] = (_Float16)(acc[i][3] + bw);
        *(ull*)(PREh + m * GDIM + n0) = p.u;
    }
}

// ---------------------------------------------------------------------------
// K2: barrier-free recurrence with backoff polling.
//   Wave (g,w) owns h element j = g*16+w. Lane l covers K-elems {q*64+l}.
//   Carried across steps: b4[gate] = pre + W_o·h64 (fully reduced, all lanes)
//   computed off the critical path during the previous step.
//   Critical path/step: poll h1 row -> 16 MACs -> 6-stage butterfly -> gates
//   -> lane0 publishes (h,tag) as one relaxed 8B agent store.
// ---------------------------------------------------------------------------
__device__ __forceinline__ float lo_f(ull v)
{ union { unsigned u; float f; } c; c.u = (unsigned)v; return c.f; }

__device__ __forceinline__ void poll_quad(const ull* __restrict__ base, int tag,
                                          int l, float* out, long long& budget)
{
    ull a0, a1, a2, a3;
    int r = 0;
    for (;;) {
        a0 = __hip_atomic_load(base +       l, __ATOMIC_RELAXED, __HIP_MEMORY_SCOPE_AGENT);
        a1 = __hip_atomic_load(base +  64 + l, __ATOMIC_RELAXED, __HIP_MEMORY_SCOPE_AGENT);
        a2 = __hip_atomic_load(base + 128 + l, __ATOMIC_RELAXED, __HIP_MEMORY_SCOPE_AGENT);
        a3 = __hip_atomic_load(base + 192 + l, __ATOMIC_RELAXED, __HIP_MEMORY_SCOPE_AGENT);
        const bool ok = ((int)(a0 >> 32) == tag) & ((int)(a1 >> 32) == tag)
                      & ((int)(a2 >> 32) == tag) & ((int)(a3 >> 32) == tag);
        if (__all((int)ok)) break;
        if (--budget < 0) break;           // bounded exit on protocol failure
        ++r;                               // wave-uniform backoff
        if (r > 16)     __builtin_amdgcn_s_sleep(8);
        else if (r > 4) __builtin_amdgcn_s_sleep(2);
    }
    out[0] = lo_f(a0); out[1] = lo_f(a1); out[2] = lo_f(a2); out[3] = lo_f(a3);
}

__device__ __forceinline__ void bfly4(float& a0, float& a1, float& a2, float& a3)
{
#pragma unroll
    for (int s = 1; s < 64; s <<= 1) {
        a0 += __shfl_xor(a0, s);
        a1 += __shfl_xor(a1, s);
        a2 += __shfl_xor(a2, s);
        a3 += __shfl_xor(a3, s);
    }
}

__global__ __launch_bounds__(1024) void k_rec(const _Float16* __restrict__ PREh,
                                              const float* __restrict__ Wih,
                                              const float* __restrict__ Whh,
                                              ull* __restrict__ HT)
{
    const int g   = blockIdx.x;        // 0..15
    const int tid = threadIdx.x;
    const int w   = tid >> 6;          // wave id 0..15
    const int l   = tid & 63;          // lane
    const int j   = g * 16 + w;        // owned h element

    // per-lane weight columns: w1v[gate][q] multiplies h[q*64+l]
    float w1v[4][4], w64v[4][4];
#pragma unroll
    for (int g4 = 0; g4 < 4; ++g4) {
        const int row = g4 * H + j;
#pragma unroll
        for (int q = 0; q < 4; ++q) {
            w1v[g4][q]  = Whh[(size_t)row * H  + q * 64 + l];
            w64v[g4][q] = Wih[(size_t)row * W5 + 4 * H + q * 64 + l];
        }
    }

    long long budget = 4000000LL;
    float h1f[4];     // h_{k-1} slice for this lane
    float b4[4];      // carried reduced (pre + W_o·h64) per gate, all lanes
    float c = 0.f;

    // ---- prologue (k=0): h64 = row 0 (zeros), h1 = row 63 (zeros)
    {
        float h64f[4];
        poll_quad(HT, 0, l, h64f, budget);
        float p0 = 0.f, p1 = 0.f, p2 = 0.f, p3 = 0.f;
#pragma unroll
        for (int q = 0; q < 4; ++q) {
            p0 += w64v[0][q] * h64f[q]; p1 += w64v[1][q] * h64f[q];
            p2 += w64v[2][q] * h64f[q]; p3 += w64v[3][q] * h64f[q];
        }
        bfly4(p0, p1, p2, p3);
        b4[0] = p0 + (float)PREh[0 * H + j];
        b4[1] = p1 + (float)PREh[1 * H + j];
        b4[2] = p2 + (float)PREh[2 * H + j];
        b4[3] = p3 + (float)PREh[3 * H + j];
        poll_quad(HT + (ull)63 * H, 63, l, h1f, budget);
    }

    for (int k = 0; k < NSTEP; ++k) {
        // ---- critical path: h1 dot + butterfly + gates + publish
        float a0 = 0.f, a1 = 0.f, a2 = 0.f, a3 = 0.f;
#pragma unroll
        for (int q = 0; q < 4; ++q) {
            a0 += w1v[0][q] * h1f[q]; a1 += w1v[1][q] * h1f[q];
            a2 += w1v[2][q] * h1f[q]; a3 += w1v[3][q] * h1f[q];
        }
        bfly4(a0, a1, a2, a3);
        const float iv = 1.f / (1.f + __expf(-(a0 + b4[0])));
        const float fv = 1.f / (1.f + __expf(-(a1 + b4[1])));
        const float gv = tanhf(a2 + b4[2]);
        const float ov = 1.f / (1.f + __expf(-(a3 + b4[3])));
        c = fv * c + iv * gv;
        const float h = ov * tanhf(c);

        if (l == 0) {
            union { float f; unsigned u; } cv; cv.f = h;
            __hip_atomic_store(&HT[(ull)(k + 64) * H + j],
                               ((ull)(unsigned)(k + 64) << 32) | cv.u,
                               __ATOMIC_RELAXED, __HIP_MEMORY_SCOPE_AGENT);
        }

        if (k + 1 < NSTEP) {
            // ---- off critical path: h64(k+1) + PRE(k+1) -> b4 for next step
            float h64f[4];
            poll_quad(HT + (ull)(k + 1) * H, k + 1, l, h64f, budget);  // 63 steps old: first-try hit
            float p0 = 0.f, p1 = 0.f, p2 = 0.f, p3 = 0.f;
#pragma unroll
            for (int q = 0; q < 4; ++q) {
                p0 += w64v[0][q] * h64f[q]; p1 += w64v[1][q] * h64f[q];
                p2 += w64v[2][q] * h64f[q]; p3 += w64v[3][q] * h64f[q];
            }
            bfly4(p0, p1, p2, p3);
            const size_t pb = (size_t)(k + 1) * GDIM + j;
            b4[0] = p0 + (float)PREh[pb];
            b4[1] = p1 + (float)PREh[pb + H];
            b4[2] = p2 + (float)PREh[pb + 2 * H];
            b4[3] = p3 + (float)PREh[pb + 3 * H];

            // ---- hot poll: h1 = row k+64 (being published right now)
            poll_quad(HT + (ull)(k + 64) * H, k + 64, l, h1f, budget);
        }
    }
}

// ---------------------------------------------------------------------------
// K3: out[b][t][l] = b_fc[l] + sum_j h_k[j] * W_fc[l][j],  k = t*64+b
//     (unchanged from R2 — proven correct)
// ---------------------------------------------------------------------------
__global__ __launch_bounds__(256) void k_fc(const ull* __restrict__ HT,
                                            const float* __restrict__ Wfc,
                                            const float* __restrict__ bfc,
                                            float* __restrict__ out)
{
    __shared__ float hl[8 * 256];
    __shared__ float wl[128 * 65];
    const int blk = blockIdx.x;     // 0..1023, k = blk*8 + kk
    const int tid = threadIdx.x;

#pragma unroll
    for (int kk = 0; kk < 8; kk++) {
        ull v = HT[((ull)(blk * 8 + kk + 64)) * H + tid];
        union { unsigned u; float f; } cc; cc.u = (unsigned)v;
        hl[kk * 256 + tid] = cc.f;
    }

    const int l = tid & 127, grp = tid >> 7;
    float a0 = 0.f, a1 = 0.f, a2 = 0.f, a3 = 0.f;

    for (int c = 0; c < 4; c++) {
        __syncthreads();
        for (int m = 0; m < 32; m++) {
            const int idx = m * 256 + tid;
            const int lr = idx >> 6, jc = idx & 63;
            wl[lr * 65 + jc] = Wfc[(size_t)lr * H + c * 64 + jc];
        }
        __syncthreads();
#pragma unroll 4
        for (int jc = 0; jc < 64; jc++) {
            const float wv = wl[l * 65 + jc];
            const int hj = c * 64 + jc;
            a0 += hl[(grp * 4 + 0) * 256 + hj] * wv;
            a1 += hl[(grp * 4 + 1) * 256 + hj] * wv;
            a2 += hl[(grp * 4 + 2) * 256 + hj] * wv;
            a3 += hl[(grp * 4 + 3) * 256 + hj] * wv;
        }
    }

    const float bias = bfc[l];
    float accs[4] = {a0, a1, a2, a3};
#pragma unroll
    for (int r = 0; r < 4; r++) {
        const int k = blk * 8 + grp * 4 + r;
        const int t = k >> 6, b = k & 63;
        out[((size_t)b * LL + t) * LBL + l] = accs[r] + bias;
    }
}

// ---------------------------------------------------------------------------
extern "C" void kernel_launch(void* const* d_in, const int* in_sizes, int n_in,
                              void* d_out, int out_size, void* d_ws, size_t ws_size,
                              hipStream_t stream)
{
    const float* x   = (const float*)d_in[0];
    const float* hi  = (const float*)d_in[1];
    const float* Wih = (const float*)d_in[2];
    const float* Whh = (const float*)d_in[3];
    const float* bih = (const float*)d_in[4];
    const float* bhh = (const float*)d_in[5];
    const float* Wfc = (const float*)d_in[6];
    const float* bfc = (const float*)d_in[7];
    float* out = (float*)d_out;

    _Float16* PREh = (_Float16*)d_ws;                        // 8192*1024 fp16 = 16 MB
    ull*      HT   = (ull*)((char*)d_ws +
                            (size_t)NSTEP * GDIM * sizeof(_Float16));  // 8256*256*8 = 16.9 MB

    const size_t need = (size_t)NSTEP * GDIM * sizeof(_Float16)
                      + (size_t)NROW * H * sizeof(ull);
    if (ws_size < need) return;   // visible failure instead of OOB writes

    k_init<<<64, H, 0, stream>>>(HT);
    k_pre<<<dim3(GDIM / 64, LL), 256, 0, stream>>>(x, hi, Wih, bih, bhh, PREh);
    k_rec<<<NWG, 1024, 0, stream>>>(PREh, Wih, Whh, HT);
    k_fc<<<NSTEP / 8, 256, 0, stream>>>(HT, Wfc, bfc, out);
}

// Round 5
// 44700.266 us; speedup vs baseline: 1.1379x; 1.1379x over previous
//
#include <hip/hip_runtime.h>
#include <math.h>

#define H    256
#define BB   64
#define LL   128
#define LBL  128
#define NSTEP (BB*LL)      // 8192 sequential cell steps
#define W5   (5*H)         // 1280 (W_ih leading dim = [x|hi|h64] layout)
#define NROW (NSTEP + 64)  // HT rows: row r holds h_{r-64}, tag r
#define NHELP 64           // helper WGs (8 row-blocks x 8 phases)
#define NPH   8            // k-phases
#define RING  256          // B4 ring slots (live window <= 128)

typedef unsigned long long ull;
typedef _Float16 half2 __attribute__((ext_vector_type(2)));
typedef _Float16 half8 __attribute__((ext_vector_type(8)));

__device__ __forceinline__ float fdot2(half2 a, half2 b, float c)
{
#if __has_builtin(__builtin_amdgcn_fdot2)
    return __builtin_amdgcn_fdot2(a, b, c, false);
#else
    return c + (float)a.x * (float)b.x + (float)a.y * (float)b.y;
#endif
}
__device__ __forceinline__ float lo_f(ull v)
{ union { unsigned u; float f; } c; c.u = (unsigned)v; return c.f; }
__device__ __forceinline__ ull tag_pack(int tag, float f)
{ union { float f; unsigned u; } c; c.f = f; return ((ull)(unsigned)tag << 32) | c.u; }
__device__ __forceinline__ float sigm(float x)
{ return __builtin_amdgcn_rcpf(1.f + __expf(-x)); }
__device__ __forceinline__ float tanh_f(float x)
{ float s = __expf(-2.f * x); return (1.f - s) * __builtin_amdgcn_rcpf(1.f + s); }

// ---------------------------------------------------------------------------
// K0: tag rows 0..63 of HT with (0.0f, tag=row) — zero initial h / out_prev.
// ---------------------------------------------------------------------------
__global__ void k_init(ull* __restrict__ HT)
{
    HT[(ull)blockIdx.x * H + threadIdx.x] = ((ull)(unsigned)blockIdx.x << 32);
}

// ---------------------------------------------------------------------------
// K_rec: 65 WGs of 512 threads.
//   blocks 0..63  = helpers: B4[k][row] = bias + Wih[row]·[x_k|hi_k|h_{k-64}]
//                   (row-block = blk&7 → 128 rows; phase = blk>>3 → k%8)
//                   gated on HT row k (64-step slack); writes tagged B4 ring.
//   block 64      = chain: the only sequential part. g = B4 + Whh·h1.
//                   Whh in VGPRs (fp16 pairs), h1 via 512B LDS broadcast,
//                   all-4-gates-per-element quad mapping, 1 barrier/step.
// ---------------------------------------------------------------------------
__global__ __launch_bounds__(512, 2)
void k_rec(const float* __restrict__ x, const float* __restrict__ hi,
           const float* __restrict__ Wih, const float* __restrict__ Whh,
           const float* __restrict__ bih, const float* __restrict__ bhh,
           ull* __restrict__ HT, ull* __restrict__ B4T)
{
    const int t = threadIdx.x;

    if (blockIdx.x < NHELP) {
        // ================= helper =================
        const int rb = blockIdx.x & 7;        // row-block
        const int ph = blockIdx.x >> 3;       // k-phase
        const int r  = rb * 128 + (t >> 2);   // gate row 0..1023
        const int q  = t & 3;                 // K-quarter (320 of 1280)

        half2 wv[160];
#pragma unroll
        for (int i = 0; i < 160; ++i) {
            float2 w = *(const float2*)&Wih[(size_t)r * W5 + q * 320 + 2 * i];
            wv[i] = half2{(_Float16)w.x, (_Float16)w.y};
        }
        const float bias = bih[r] + bhh[r];

        __shared__ __align__(16) _Float16 fl[1280];   // [x(512)|hi(512)|h64(256)]
        long long budget = 200000000LL;

        for (int k = ph; k < NSTEP; k += NPH) {
            const int b = k & 63, tt = k >> 6;
            if (t < 256) {
                float2 v = *(const float2*)(x + ((size_t)b * LL + tt) * 512 + 2 * t);
                fl[2 * t] = (_Float16)v.x; fl[2 * t + 1] = (_Float16)v.y;
            } else {
                float2 v = *(const float2*)(hi + ((size_t)b * LL + tt) * 512 + 2 * (t - 256));
                fl[512 + 2 * (t - 256)] = (_Float16)v.x;
                fl[513 + 2 * (t - 256)] = (_Float16)v.y;
            }
            if (t < 256) {       // h_{k-64} = HT row k (tagged k)
                ull v; int rnd = 0;
                for (;;) {
                    v = __hip_atomic_load(&HT[(ull)k * H + t], __ATOMIC_RELAXED,
                                          __HIP_MEMORY_SCOPE_AGENT);
                    if ((int)(v >> 32) == k) break;
                    if (--budget < 0) break;
                    if (++rnd > 8) __builtin_amdgcn_s_sleep(8);   // off critical path
                }
                fl[1024 + t] = (_Float16)lo_f(v);
            }
            __syncthreads();

            const half8* hp = (const half8*)&fl[q * 320];   // 40 x 16B, bcast
            float a0 = 0.f, a1 = 0.f, a2 = 0.f, a3 = 0.f;
#pragma unroll
            for (int i = 0; i < 40; ++i) {
                half8 hv = hp[i];
                a0 = fdot2(wv[4 * i + 0], half2{hv[0], hv[1]}, a0);
                a1 = fdot2(wv[4 * i + 1], half2{hv[2], hv[3]}, a1);
                a2 = fdot2(wv[4 * i + 2], half2{hv[4], hv[5]}, a2);
                a3 = fdot2(wv[4 * i + 3], half2{hv[6], hv[7]}, a3);
            }
            float acc = (a0 + a1) + (a2 + a3);
            acc += __shfl_xor(acc, 1);
            acc += __shfl_xor(acc, 2);
            if (q == 0)
                __hip_atomic_store(&B4T[(ull)(k & (RING - 1)) * 1024 + r],
                                   tag_pack(k, acc + bias),
                                   __ATOMIC_RELAXED, __HIP_MEMORY_SCOPE_AGENT);
            __syncthreads();    // WAR on fl before next k's stores
        }
        return;
    }

    // ================= chain (single CU) =================
    const int q   = t & 3;        // h1 K-quarter (64 elems)
    const int rid = t >> 2;       // 0..127; rows rid+128m; m = 2*gate + j7
                                  // owns elements j0=rid, j1=rid+128 (all 4 gates)
    half2 wh[8][32];
#pragma unroll
    for (int m = 0; m < 8; ++m) {
        const size_t row = rid + 128 * m;
#pragma unroll
        for (int i = 0; i < 32; ++i) {
            float2 w = *(const float2*)&Whh[row * H + q * 64 + 2 * i];
            wh[m][i] = half2{(_Float16)w.x, (_Float16)w.y};
        }
    }

    __shared__ __align__(16) _Float16 h1b[2][256];
    if (t < 256) h1b[0][t] = (_Float16)0.f;    // h_{-1} = 0
    __syncthreads();

    long long budget = 200000000LL;
    float c0 = 0.f, c1 = 0.f;

    ull b4v[8];
#pragma unroll
    for (int m = 0; m < 8; ++m)
        b4v[m] = __hip_atomic_load(&B4T[rid + 128 * m], __ATOMIC_RELAXED,
                                   __HIP_MEMORY_SCOPE_AGENT);

    for (int k = 0; k < NSTEP; ++k) {
        const int cb = k & 1;

        // validate prefetched B4 (expected first-try; helpers run 64 steps ahead)
        {
            int rnd = 0;
            for (;;) {
                bool ok = true;
#pragma unroll
                for (int m = 0; m < 8; ++m) ok &= ((int)(b4v[m] >> 32) == k);
                if (__all((int)ok)) break;
                if (--budget < 0) break;
                if (++rnd > 4) __builtin_amdgcn_s_sleep(1);
                const ull* bp = &B4T[(ull)(k & (RING - 1)) * 1024 + rid];
#pragma unroll
                for (int m = 0; m < 8; ++m)
                    b4v[m] = __hip_atomic_load(bp + 128 * m, __ATOMIC_RELAXED,
                                               __HIP_MEMORY_SCOPE_AGENT);
            }
        }

        // Whh·h1: 8 rows x 64 K (fp16 pairs, fp32 accum), LDS broadcast reads
        const half8* hp = (const half8*)&h1b[cb][q * 64];
        float sA[8] = {0,0,0,0,0,0,0,0}, sB[8] = {0,0,0,0,0,0,0,0};
#pragma unroll
        for (int i = 0; i < 8; ++i) {
            half8 hv = hp[i];
            half2 p0 = half2{hv[0], hv[1]}, p1 = half2{hv[2], hv[3]};
            half2 p2 = half2{hv[4], hv[5]}, p3 = half2{hv[6], hv[7]};
#pragma unroll
            for (int m = 0; m < 8; ++m) {
                sA[m] = fdot2(wh[m][4 * i + 0], p0, sA[m]);
                sB[m] = fdot2(wh[m][4 * i + 1], p1, sB[m]);
                sA[m] = fdot2(wh[m][4 * i + 2], p2, sA[m]);
                sB[m] = fdot2(wh[m][4 * i + 3], p3, sB[m]);
            }
        }
        float g[8];
#pragma unroll
        for (int m = 0; m < 8; ++m) {
            float s = sA[m] + sB[m];
            s += __shfl_xor(s, 1);     // reduce over the K-quad
            s += __shfl_xor(s, 2);
            g[m] = s + lo_f(b4v[m]);
        }
        // m = 2*gate + j7: elem j0=rid -> m=0,2,4,6 ; elem j1=rid+128 -> m=1,3,5,7
        const float i0 = sigm(g[0]), f0 = sigm(g[2]), q0 = tanh_f(g[4]), o0 = sigm(g[6]);
        const float i1 = sigm(g[1]), f1 = sigm(g[3]), q1 = tanh_f(g[5]), o1 = sigm(g[7]);
        c0 = f0 * c0 + i0 * q0;  const float h0 = o0 * tanh_f(c0);
        c1 = f1 * c1 + i1 * q1;  const float h1v = o1 * tanh_f(c1);

        if (q == 0) {            // publish fp32 h (for helpers + k_fc)
            ull* hp_ = &HT[(ull)(k + 64) * H + rid];
            __hip_atomic_store(hp_,       tag_pack(k + 64, h0),
                               __ATOMIC_RELAXED, __HIP_MEMORY_SCOPE_AGENT);
            __hip_atomic_store(hp_ + 128, tag_pack(k + 64, h1v),
                               __ATOMIC_RELAXED, __HIP_MEMORY_SCOPE_AGENT);
        } else if (q == 1) {     // next-step h1 into the other LDS buffer
            h1b[cb ^ 1][rid]       = (_Float16)h0;
            h1b[cb ^ 1][rid + 128] = (_Float16)h1v;
        }

        if (k + 1 < NSTEP) {     // prefetch B4[k+1] (validated next iteration)
            const ull* bp = &B4T[(ull)((k + 1) & (RING - 1)) * 1024 + rid];
#pragma unroll
            for (int m = 0; m < 8; ++m)
                b4v[m] = __hip_atomic_load(bp + 128 * m, __ATOMIC_RELAXED,
                                           __HIP_MEMORY_SCOPE_AGENT);
        }
        __syncthreads();
    }
}

// ---------------------------------------------------------------------------
// K_fc: out[b][t][l] = b_fc[l] + sum_j h_k[j] * W_fc[l][j],  k = t*64+b
//       (R2-proven; reads fp32 h from tagged HT rows)
// ---------------------------------------------------------------------------
__global__ __launch_bounds__(256) void k_fc(const ull* __restrict__ HT,
                                            const float* __restrict__ Wfc,
                                            const float* __restrict__ bfc,
                                            float* __restrict__ out)
{
    __shared__ float hl[8 * 256];
    __shared__ float wl[128 * 65];
    const int blk = blockIdx.x;
    const int tid = threadIdx.x;

#pragma unroll
    for (int kk = 0; kk < 8; kk++)
        hl[kk * 256 + tid] = lo_f(HT[((ull)(blk * 8 + kk + 64)) * H + tid]);

    const int l = tid & 127, grp = tid >> 7;
    float a0 = 0.f, a1 = 0.f, a2 = 0.f, a3 = 0.f;

    for (int c = 0; c < 4; c++) {
        __syncthreads();
        for (int m = 0; m < 32; m++) {
            const int idx = m * 256 + tid;
            const int lr = idx >> 6, jc = idx & 63;
            wl[lr * 65 + jc] = Wfc[(size_t)lr * H + c * 64 + jc];
        }
        __syncthreads();
#pragma unroll 4
        for (int jc = 0; jc < 64; jc++) {
            const float wv = wl[l * 65 + jc];
            const int hj = c * 64 + jc;
            a0 += hl[(grp * 4 + 0) * 256 + hj] * wv;
            a1 += hl[(grp * 4 + 1) * 256 + hj] * wv;
            a2 += hl[(grp * 4 + 2) * 256 + hj] * wv;
            a3 += hl[(grp * 4 + 3) * 256 + hj] * wv;
        }
    }

    const float bias = bfc[l];
    float accs[4] = {a0, a1, a2, a3};
#pragma unroll
    for (int r = 0; r < 4; r++) {
        const int k = blk * 8 + grp * 4 + r;
        const int tt = k >> 6, b = k & 63;
        out[((size_t)b * LL + tt) * LBL + l] = accs[r] + bias;
    }
}

// ---------------------------------------------------------------------------
extern "C" void kernel_launch(void* const* d_in, const int* in_sizes, int n_in,
                              void* d_out, int out_size, void* d_ws, size_t ws_size,
                              hipStream_t stream)
{
    const float* x   = (const float*)d_in[0];
    const float* hi  = (const float*)d_in[1];
    const float* Wih = (const float*)d_in[2];
    const float* Whh = (const float*)d_in[3];
    const float* bih = (const float*)d_in[4];
    const float* bhh = (const float*)d_in[5];
    const float* Wfc = (const float*)d_in[6];
    const float* bfc = (const float*)d_in[7];
    float* out = (float*)d_out;

    ull* HT  = (ull*)d_ws;                                   // 8256*256*8 = 16.9 MB
    ull* B4T = HT + (size_t)NROW * H;                        // 256*1024*8 = 2 MB

    const size_t need = ((size_t)NROW * H + (size_t)RING * 1024) * sizeof(ull);
    if (ws_size < need) return;   // visible failure instead of OOB writes

    k_init<<<64, H, 0, stream>>>(HT);
    k_rec<<<NHELP + 1, 512, 0, stream>>>(x, hi, Wih, Whh, bih, bhh, HT, B4T);
    k_fc<<<NSTEP / 8, 256, 0, stream>>>(HT, Wfc, bfc, out);
}

// Round 7
// 18892.688 us; speedup vs baseline: 2.6922x; 2.3660x over previous
//
#include <hip/hip_runtime.h>
#include <math.h>

#define H    256
#define BB   64
#define LL   128
#define LBL  128
#define NSTEP (BB*LL)      // 8192 sequential cell steps
#define W5   (5*H)         // 1280 (W_ih leading dim)
#define NROW (NSTEP + 64)  // HT rows: row r holds h_{r-64}, tag r
#define NHELP 64           // helper WGs (8 row-blocks x 8 phases)
#define NPH   8
#define RING  256          // B4 ring slots

typedef unsigned long long ull;
typedef _Float16 half2 __attribute__((ext_vector_type(2)));
typedef _Float16 half8 __attribute__((ext_vector_type(8)));

__device__ __forceinline__ float fdot2(half2 a, half2 b, float c)
{
#if __has_builtin(__builtin_amdgcn_fdot2)
    return __builtin_amdgcn_fdot2(a, b, c, false);
#else
    return c + (float)a.x * (float)b.x + (float)a.y * (float)b.y;
#endif
}
__device__ __forceinline__ float lo_f(ull v)
{ union { unsigned u; float f; } c; c.u = (unsigned)v; return c.f; }
__device__ __forceinline__ ull tag_pack(int tag, float f)
{ union { float f; unsigned u; } c; c.f = f; return ((ull)(unsigned)tag << 32) | c.u; }
__device__ __forceinline__ float sigm(float x)
{ return __builtin_amdgcn_rcpf(1.f + __expf(-x)); }
__device__ __forceinline__ float tanh_f(float x)
{ float s = __expf(-2.f * x); return (1.f - s) * __builtin_amdgcn_rcpf(1.f + s); }

// ---------------------------------------------------------------------------
__global__ void k_init(ull* __restrict__ HT)
{
    HT[(ull)blockIdx.x * H + threadIdx.x] = ((ull)(unsigned)blockIdx.x << 32);
}

// ---------------------------------------------------------------------------
// K_rec: 65 WGs x 512 threads.
//  blocks 0..63 helpers: B4[k][row] = bias + Wih[row]·[x_k|hi_k|h_{k-64}] (fp16)
//  block 64 chain: g = B4 + Whh·h1. Whh: 6 rows/thread in VGPR fp16,
//  2 rows/thread in LDS (stride-33-word layout, conflict-free sequential).
// ---------------------------------------------------------------------------
__global__ __launch_bounds__(512, 1)
void k_rec(const float* __restrict__ x, const float* __restrict__ hi,
           const float* __restrict__ Wih, const float* __restrict__ Whh,
           const float* __restrict__ bih, const float* __restrict__ bhh,
           ull* __restrict__ HT, ull* __restrict__ B4T)
{
    const int t = threadIdx.x;

    if (blockIdx.x < NHELP) {
        // ================= helper =================
        const int rb = blockIdx.x & 7;        // row-block (128 rows)
        const int ph = blockIdx.x >> 3;       // k-phase
        const int r  = rb * 128 + (t >> 2);   // gate row 0..1023
        const int q  = t & 3;                 // K-quarter (320 of 1280)

        half2 wv[160];
#pragma unroll
        for (int i = 0; i < 160; ++i) {
            float2 w = *(const float2*)&Wih[(size_t)r * W5 + q * 320 + 2 * i];
            wv[i] = half2{(_Float16)w.x, (_Float16)w.y};
        }
        const float bias = bih[r] + bhh[r];

        // padded quarters: feature f lives at f + 8*(f/320); quarter q base 328q
        __shared__ __align__(16) _Float16 fl[1312];
        long long budget = 200000000LL;

        for (int k = ph; k < NSTEP; k += NPH) {
            const int b = k & 63, tt = k >> 6;
            if (t < 256) {
                float2 v = *(const float2*)(x + ((size_t)b * LL + tt) * 512 + 2 * t);
                const int f0 = 2 * t;
                fl[f0 + 8 * (f0 / 320)]           = (_Float16)v.x;
                fl[f0 + 1 + 8 * ((f0 + 1) / 320)] = (_Float16)v.y;
            } else {
                float2 v = *(const float2*)(hi + ((size_t)b * LL + tt) * 512 + 2 * (t - 256));
                const int f0 = 512 + 2 * (t - 256);
                fl[f0 + 8 * (f0 / 320)]           = (_Float16)v.x;
                fl[f0 + 1 + 8 * ((f0 + 1) / 320)] = (_Float16)v.y;
            }
            if (t < 256) {       // h_{k-64} = HT row k (tag k); 64-step slack
                ull v; int rnd = 0;
                for (;;) {
                    v = __hip_atomic_load(&HT[(ull)k * H + t], __ATOMIC_RELAXED,
                                          __HIP_MEMORY_SCOPE_AGENT);
                    if ((int)(v >> 32) == k) break;
                    if (--budget < 0) break;
                    if (++rnd > 8) __builtin_amdgcn_s_sleep(8);
                }
                fl[1048 + t] = (_Float16)lo_f(v);   // f=1024+t -> +24 pad
            }
            __syncthreads();

            const half8* hp = (const half8*)&fl[328 * q];   // broadcast, conflict-free
            float a0 = 0.f, a1 = 0.f, a2 = 0.f, a3 = 0.f;
#pragma unroll
            for (int i = 0; i < 40; ++i) {
                half8 hv = hp[i];
                const half2* pp = (const half2*)&hv;
                a0 = fdot2(wv[4 * i + 0], pp[0], a0);
                a1 = fdot2(wv[4 * i + 1], pp[1], a1);
                a2 = fdot2(wv[4 * i + 2], pp[2], a2);
                a3 = fdot2(wv[4 * i + 3], pp[3], a3);
            }
            float acc = (a0 + a1) + (a2 + a3);
            acc += __shfl_xor(acc, 1);
            acc += __shfl_xor(acc, 2);
            if (q == 0)
                __hip_atomic_store(&B4T[(ull)(k & (RING - 1)) * 1024 + r],
                                   tag_pack(k, acc + bias),
                                   __ATOMIC_RELAXED, __HIP_MEMORY_SCOPE_AGENT);
            __syncthreads();    // WAR on fl
        }
        return;
    }

    // ================= chain (single CU) =================
    const int q   = t & 3;        // K-quarter of h1: elements [64q, 64q+64)
    const int rid = t >> 2;       // 0..127; rows rid+128m; m = 2*gate + j7
                                  // elems j0=rid (m even), j1=rid+128 (m odd)
    // VGPR weights: rows m=0..5 (gates i,f,g~ for both elems), 192 regs
    half2 wv6[6][32];
#pragma unroll
    for (int m = 0; m < 6; ++m) {
        const size_t row = rid + 128 * m;
#pragma unroll
        for (int i = 0; i < 32; ++i) {
            float2 w = *(const float2*)&Whh[row * H + q * 64 + 2 * i];
            wv6[m][i] = half2{(_Float16)w.x, (_Float16)w.y};
        }
    }

    // LDS weights: rows m=6,7 (o-gate). Thread-stride 33 words -> banks (t+ii)%32
    __shared__ half2 wl[2][512 * 33];
    __shared__ __align__(16) _Float16 h1r[2][4 * 336];   // 4 full replicas, stride 336
#pragma unroll
    for (int m2 = 0; m2 < 2; ++m2) {
        const size_t row = rid + 128 * (6 + m2);
#pragma unroll
        for (int i = 0; i < 32; ++i) {
            float2 w = *(const float2*)&Whh[row * H + q * 64 + 2 * i];
            wl[m2][t * 33 + i] = half2{(_Float16)w.x, (_Float16)w.y};
        }
    }
    h1r[0][336 * q + rid]       = (_Float16)0.f;   // h_{-1} = 0 (own slots)
    h1r[0][336 * q + rid + 128] = (_Float16)0.f;
    __syncthreads();

    long long budget = 200000000LL;
    float c0 = 0.f, c1 = 0.f;

    ull b4v[8];
#pragma unroll
    for (int m = 0; m < 8; ++m)
        b4v[m] = __hip_atomic_load(&B4T[rid + 128 * m], __ATOMIC_RELAXED,
                                   __HIP_MEMORY_SCOPE_AGENT);

    for (int k = 0; k < NSTEP; ++k) {
        const int cb = k & 1, nb = cb ^ 1;

        // validate B4[k] (expected first-try: written ~63 steps ago)
        {
            int rnd = 0;
            for (;;) {
                bool ok = true;
#pragma unroll
                for (int m = 0; m < 8; ++m) ok &= ((int)(b4v[m] >> 32) == k);
                if (__all((int)ok)) break;
                if (--budget < 0) break;
                if (++rnd > 4) __builtin_amdgcn_s_sleep(1);
                const ull* bp = &B4T[(ull)(k & (RING - 1)) * 1024 + rid];
#pragma unroll
                for (int m = 0; m < 8; ++m)
                    b4v[m] = __hip_atomic_load(bp + 128 * m, __ATOMIC_RELAXED,
                                               __HIP_MEMORY_SCOPE_AGENT);
            }
        }
        float b4f[8];
#pragma unroll
        for (int m = 0; m < 8; ++m) b4f[m] = lo_f(b4v[m]);

        // Whh·h1: 6 VGPR rows + 2 LDS rows, 64 K each (fp16 pairs, f32 accum)
        // FIX vs R6: read this quarter's K-slice [64q,64q+64) -> base 336q+64q
        const half8* hp = (const half8*)&h1r[cb][336 * q + 64 * q];
        const half2* wb0 = &wl[0][t * 33];
        const half2* wb1 = &wl[1][t * 33];
        float acc[8] = {0,0,0,0,0,0,0,0};
#pragma unroll
        for (int i = 0; i < 8; ++i) {
            half8 hv = hp[i];
            const half2* pp = (const half2*)&hv;
#pragma unroll
            for (int jj = 0; jj < 4; ++jj) {
                const int ii = 4 * i + jj;
                const half2 p = pp[jj];
                acc[0] = fdot2(wv6[0][ii], p, acc[0]);
                acc[1] = fdot2(wv6[1][ii], p, acc[1]);
                acc[2] = fdot2(wv6[2][ii], p, acc[2]);
                acc[3] = fdot2(wv6[3][ii], p, acc[3]);
                acc[4] = fdot2(wv6[4][ii], p, acc[4]);
                acc[5] = fdot2(wv6[5][ii], p, acc[5]);
                acc[6] = fdot2(wb0[ii],    p, acc[6]);
                acc[7] = fdot2(wb1[ii],    p, acc[7]);
            }
        }
        float g[8];
#pragma unroll
        for (int m = 0; m < 8; ++m) {
            float s = acc[m];
            s += __shfl_xor(s, 1);     // reduce over K-quad (aligned 4-lane group)
            s += __shfl_xor(s, 2);
            g[m] = s + b4f[m];
        }

        // prefetch B4[k+1] AFTER the dot window (register-pressure + latency
        // hidden under gates/publish/barrier; validated next iteration)
        if (k + 1 < NSTEP) {
            const ull* bp = &B4T[(ull)((k + 1) & (RING - 1)) * 1024 + rid];
#pragma unroll
            for (int m = 0; m < 8; ++m)
                b4v[m] = __hip_atomic_load(bp + 128 * m, __ATOMIC_RELAXED,
                                           __HIP_MEMORY_SCOPE_AGENT);
        }

        // m = 2*gate + j7
        const float i0 = sigm(g[0]), f0 = sigm(g[2]), q0 = tanh_f(g[4]), o0 = sigm(g[6]);
        const float i1 = sigm(g[1]), f1 = sigm(g[3]), q1 = tanh_f(g[5]), o1 = sigm(g[7]);
        c0 = f0 * c0 + i0 * q0;  const float h0  = o0 * tanh_f(c0);
        c1 = f1 * c1 + i1 * q1;  const float h1v = o1 * tanh_f(c1);

        if (q == 0) {            // publish fp32 h (helpers + k_fc)
            ull* hpub = &HT[(ull)(k + 64) * H + rid];
            __hip_atomic_store(hpub,       tag_pack(k + 64, h0),
                               __ATOMIC_RELAXED, __HIP_MEMORY_SCOPE_AGENT);
            __hip_atomic_store(hpub + 128, tag_pack(k + 64, h1v),
                               __ATOMIC_RELAXED, __HIP_MEMORY_SCOPE_AGENT);
        }
        // every thread writes its 2 elements into its own replica (next buffer)
        h1r[nb][336 * q + rid]       = (_Float16)h0;
        h1r[nb][336 * q + rid + 128] = (_Float16)h1v;
        __syncthreads();
    }
}

// ---------------------------------------------------------------------------
// K_fc: out[b][t][l] = b_fc[l] + sum_j h_k[j] * W_fc[l][j],  k = t*64+b
// ---------------------------------------------------------------------------
__global__ __launch_bounds__(256) void k_fc(const ull* __restrict__ HT,
                                            const float* __restrict__ Wfc,
                                            const float* __restrict__ bfc,
                                            float* __restrict__ out)
{
    __shared__ float hl[8 * 256];
    __shared__ float wl[128 * 65];
    const int blk = blockIdx.x;
    const int tid = threadIdx.x;

#pragma unroll
    for (int kk = 0; kk < 8; kk++)
        hl[kk * 256 + tid] = lo_f(HT[((ull)(blk * 8 + kk + 64)) * H + tid]);

    const int l = tid & 127, grp = tid >> 7;
    float a0 = 0.f, a1 = 0.f, a2 = 0.f, a3 = 0.f;

    for (int c = 0; c < 4; c++) {
        __syncthreads();
        for (int m = 0; m < 32; m++) {
            const int idx = m * 256 + tid;
            const int lr = idx >> 6, jc = idx & 63;
            wl[lr * 65 + jc] = Wfc[(size_t)lr * H + c * 64 + jc];
        }
        __syncthreads();
#pragma unroll 4
        for (int jc = 0; jc < 64; jc++) {
            const float wv = wl[l * 65 + jc];
            const int hj = c * 64 + jc;
            a0 += hl[(grp * 4 + 0) * 256 + hj] * wv;
            a1 += hl[(grp * 4 + 1) * 256 + hj] * wv;
            a2 += hl[(grp * 4 + 2) * 256 + hj] * wv;
            a3 += hl[(grp * 4 + 3) * 256 + hj] * wv;
        }
    }

    const float bias = bfc[l];
    float accs[4] = {a0, a1, a2, a3};
#pragma unroll
    for (int r = 0; r < 4; r++) {
        const int k = blk * 8 + grp * 4 + r;
        const int tt = k >> 6, b = k & 63;
        out[((size_t)b * LL + tt) * LBL + l] = accs[r] + bias;
    }
}

// ---------------------------------------------------------------------------
extern "C" void kernel_launch(void* const* d_in, const int* in_sizes, int n_in,
                              void* d_out, int out_size, void* d_ws, size_t ws_size,
                              hipStream_t stream)
{
    const float* x   = (const float*)d_in[0];
    const float* hi  = (const float*)d_in[1];
    const float* Wih = (const float*)d_in[2];
    const float* Whh = (const float*)d_in[3];
    const float* bih = (const float*)d_in[4];
    const float* bhh = (const float*)d_in[5];
    const float* Wfc = (const float*)d_in[6];
    const float* bfc = (const float*)d_in[7];
    float* out = (float*)d_out;

    ull* HT  = (ull*)d_ws;                                   // 8256*256*8 = 16.9 MB
    ull* B4T = HT + (size_t)NROW * H;                        // 256*1024*8 = 2 MB

    const size_t need = ((size_t)NROW * H + (size_t)RING * 1024) * sizeof(ull);
    if (ws_size < need) return;   // visible failure instead of OOB writes

    k_init<<<64, H, 0, stream>>>(HT);
    k_rec<<<NHELP + 1, 512, 0, stream>>>(x, hi, Wih, Whh, bih, bhh, HT, B4T);
    k_fc<<<NSTEP / 8, 256, 0, stream>>>(HT, Wfc, bfc, out);
}